// Round 4
// baseline (253.381 us; speedup 1.0000x reference)
//
#include <hip/hip_runtime.h>

#define N_CELLTYPE 50
#define M_PER_CT   2000
#define N_FEATURE  20000
#define N_CELL     512
#define R_TOTAL    (N_CELLTYPE * M_PER_CT)   // 100000 rows of z
#define TR         256                       // rows per tile (tail tile: 160 rows)
#define TC         32                        // cols per tile (512/32 = 16 exact)
#define NTHREADS   512
#define NRT        ((R_TOTAL + TR - 1) / TR) // 391 row tiles (390*256 + 160)
#define NCT        (N_CELL / TC)             // 16 col tiles
#define HALF       (8 * NRT)                 // 3128 blocks per phase (8 XCDs x 391)

typedef float vfloat4 __attribute__((ext_vector_type(4)));

// Round 4: XCD-sliced gather. Body identical to R1/R3 (verified twice); only
// the block->(row,col)-tile mapping and nt-stores change.
//   Theory: all 4 prior variants read ~205MB of gather traffic through the
//   L3/fabric read path (~3-4 TB/s aggregate) because no variant gave the
//   re-reads L2 locality -> ~119us plateau regardless of write pattern.
//   Fix: col-tile j's x-slice is 20000x128B = 2.56MB < 4MB L2. Pin all 391
//   row-tile blocks of col-tile j to XCD j%8 (dispatch round-robins XCDs),
//   phase 0 = col-tiles 0-7, phase 1 = 8-15. Each XCD keeps one 2.56MB slice
//   L2-resident; ~164MB of re-reads become L2 hits (~6us at 34.5 TB/s),
//   HBM reads drop to the 41MB compulsory.
//   nt-stores restored: the per-XCD write stream (12.8MB/phase) must NOT
//   allocate in L2 or it evicts the read slice. (R1 vs R3 proved nt alone is
//   perf-neutral, so any delta here attributes to the mapping.)
__global__ __launch_bounds__(NTHREADS) void ct_scale_transpose(
    const float* __restrict__ x, const float* __restrict__ w,
    const int* __restrict__ idx, float* __restrict__ out) {
  __shared__ float tile[TC][TR];   // 32KB; + srow/sw = 34KB -> 4 blocks/CU
  __shared__ int   srow[TR];
  __shared__ float sw[TR];

  // b -> (rt, ct) with ct%8 == b%8 (XCD round-robin) and col-tiles split into
  // two temporal phases of 8 (one per XCD). HALF = 8*391 = 3128, grid = 6256.
  const int b     = blockIdx.x;
  const int phase = (b >= HALF) ? 1 : 0;
  const int i     = b - phase * HALF;
  const int rt    = i >> 3;                  // 0..390
  const int ct    = (phase << 3) + (i & 7);  // 0..15, ct%8 == i%8
  const int r0 = rt * TR;
  const int c0 = ct * TC;
  const int t  = threadIdx.x;

  if (t < TR) {
    const int r = r0 + t;
    if (r < R_TOTAL) {
      srow[t] = idx[r];
      sw[t]   = w[r / M_PER_CT];
    } else {              // tail tile: harmless dummy row, output is guarded
      srow[t] = 0;
      sw[t]   = 0.0f;
    }
  }
  __syncthreads();

  // Load phase: 256 rows x 8 float4 = 2048 float4, 4/thread.
  // Per wave instr: 8 rows x 128B aligned line segments (from the XCD's
  // L2-resident 2.56MB col-slice after first touch).
#pragma unroll
  for (int i2 = 0; i2 < 4; ++i2) {
    const int linear = i2 * NTHREADS + t;
    const int row = linear >> 3;    // 0..255
    const int q   = linear & 7;     // float4 index within the 32-col slice
    const float4 v = *reinterpret_cast<const float4*>(
        x + (long)srow[row] * N_CELL + c0 + q * 4);
    const float s = sw[row];
    const float e[4] = {v.x * s, v.y * s, v.z * s, v.w * s};
#pragma unroll
    for (int j = 0; j < 4; ++j) {
      const int c    = q * 4 + j;
      const int rswz = row ^ (((c >> 1) & 7) << 2);  // XOR-swizzle bits 2..4
      tile[c][rswz] = e[j];
    }
  }
  __syncthreads();

  // Store phase: 32 cols x 64 float4-chunks = 2048 float4, 4/thread.
  // c wave-uniform -> each wave-store = 1KB contiguous aligned burst.
#pragma unroll
  for (int i2 = 0; i2 < 4; ++i2) {
    const int linear = i2 * NTHREADS + t;
    const int c    = linear >> 6;               // 0..31, fixed per wave
    const int lane = linear & 63;               // 4-row chunk index
    const int m    = lane ^ ((c >> 1) & 7);     // de-swizzled float4 slot
    const int r    = r0 + lane * 4;
    if (r < R_TOTAL) {                          // tail tile: lanes 0..39 active
      const vfloat4 v = *reinterpret_cast<const vfloat4*>(&tile[c][m * 4]);
      __builtin_nontemporal_store(
          v, reinterpret_cast<vfloat4*>(out + (long)(c0 + c) * R_TOTAL + r));
    }
  }
}

extern "C" void kernel_launch(void* const* d_in, const int* in_sizes, int n_in,
                              void* d_out, int out_size, void* d_ws, size_t ws_size,
                              hipStream_t stream) {
  const float* x   = (const float*)d_in[0];
  const float* w   = (const float*)d_in[1];
  const int*   idx = (const int*)d_in[2];
  float*       out = (float*)d_out;

  ct_scale_transpose<<<dim3(2 * HALF), dim3(NTHREADS), 0, stream>>>(x, w, idx, out);
}